// Round 1
// 973.704 us; speedup vs baseline: 1.0444x; 1.0444x over previous
//
#include <hip/hip_runtime.h>
#include <math.h>

#define T_LEN 3000
#define HID 64

typedef _Float16 f16;
typedef f16 f16x8 __attribute__((ext_vector_type(8)));
typedef float f32x4 __attribute__((ext_vector_type(4)));

__device__ __forceinline__ float sigmoid_f(float v) {
    return __builtin_amdgcn_rcpf(1.0f + __expf(-v));
}
__device__ __forceinline__ float tanh_f(float v) {
    return fmaf(2.0f, __builtin_amdgcn_rcpf(1.0f + __expf(-2.0f * v)), -1.0f);
}

// One wave per batch element, zero s_barriers (single-wave block, in-order DS).
// R7: matvec moved from 96x v_dot2_f32_f16 (VALU critical path, ~2-4cy each)
// to 24x v_mfma_f32_16x16x32_f16 (~4.85cy each on the matrix pipe, 12
// independent 2-chains). A operand = h broadcast into all 16 rows: lane l
// only needs h[8*(l>>4) .. +7] per K-half -> 2x ds_read_b128 (was 8).
// B operand = static W_hh f16 fragments, 12 tiles x 2 K-halves x 4 VGPR = 96
// VGPR, register-resident (waves_per_eu(1,1): occupancy already 1 wave/CU,
// so burning VGPRs is free). D layout (m89-verified): col = lane&15, rows
// replicated -> lane l's unit value sits in tile l>>4, reg 0; a 3-deep
// cndmask select extracts it (no cross-lane exchange).
// Tile order r -> n -> z so exp/rcp latency overlaps MFMA issue.
__global__
__attribute__((amdgpu_flat_work_group_size(64, 64), amdgpu_waves_per_eu(1, 1)))
void gru_mfma(
    const float* __restrict__ x,     // (B, T, 1)
    const float* __restrict__ W_ih,  // (192, 1)
    const float* __restrict__ W_hh,  // (192, 64)
    const float* __restrict__ b_ih,  // (192,)
    const float* __restrict__ b_hh,  // (192,)
    const float* __restrict__ W_fc,  // (1, 64)
    const float* __restrict__ b_fc,  // (1,)
    float* __restrict__ out)         // (B,)
{
    const int b   = blockIdx.x;
    const int l   = threadIdx.x;   // 0..63; lane l owns hidden unit l
    const int col = l & 15;        // unit-within-tile / D column
    const int grp = l >> 4;        // k-group (A/B k = 8*grp + j, +32 per half)
    const long xbase = (long)b * T_LEN;

    __shared__ __align__(16) f16 h_lds[HID];   // 128 B
    __shared__ float x_lds[64];

    // ---- one-time: W_hh -> B fragments (f16), 12 tiles x 2 K-halves ----
    // B slot (lane l, elem j) = W_hh[16*t + (l&15)][8*(l>>4) + 32*half + j]
    f16x8 Bf[12][2];
#pragma unroll
    for (int t = 0; t < 12; ++t) {
#pragma unroll
        for (int hf = 0; hf < 2; ++hf) {
            const float* p = W_hh + (size_t)(16 * t + col) * HID + 8 * grp + 32 * hf;
            const float4 a = *reinterpret_cast<const float4*>(p);
            const float4 c = *reinterpret_cast<const float4*>(p + 4);
            f16x8 v;
            v[0] = (f16)a.x; v[1] = (f16)a.y; v[2] = (f16)a.z; v[3] = (f16)a.w;
            v[4] = (f16)c.x; v[5] = (f16)c.y; v[6] = (f16)c.z; v[7] = (f16)c.w;
            Bf[t][hf] = v;
        }
    }

    const float wihr = W_ih[l],        wihz = W_ih[64 + l],   wihn = W_ih[128 + l];
    const float br   = b_ih[l]        + b_hh[l];
    const float bz   = b_ih[64 + l]   + b_hh[64 + l];
    const float bin  = b_ih[128 + l];
    const float bhn  = b_hh[128 + l];

    // init h and first x chunk (single wave: DS in-order, no s_barrier needed)
    h_lds[l] = (f16)0.0f;
    x_lds[l] = x[xbase + l];
    float xnxt = (64 + l < T_LEN) ? x[xbase + 64 + l] : 0.0f;
    float h = 0.0f;  // lane l holds h[l] in fp32
    __builtin_amdgcn_wave_barrier();

    const f16x8* hv = reinterpret_cast<const f16x8*>(h_lds);
    const f32x4 zf = {0.f, 0.f, 0.f, 0.f};
    const bool s0 = (grp & 1) != 0;
    const bool s1 = (grp & 2) != 0;

    for (int t = 0; t < T_LEN; ++t) {
        const int j = t & 63;
        const float xt = x_lds[j];                 // uniform LDS broadcast
        // A operand, rows replicated: lane needs h[8*grp + j'] (+32 for half 1)
        const f16x8 A0 = hv[grp];                  // ds_read_b128
        const f16x8 A1 = hv[grp + 4];              // ds_read_b128

        // ---- r gate: tiles 0..3 (units 0..63) ----
        f32x4 accr[4];
#pragma unroll
        for (int q = 0; q < 4; ++q) {
            f32x4 c0 = __builtin_amdgcn_mfma_f32_16x16x32_f16(A0, Bf[q][0], zf, 0, 0, 0);
            accr[q]  = __builtin_amdgcn_mfma_f32_16x16x32_f16(A1, Bf[q][1], c0, 0, 0, 0);
        }
        const float ar = s1 ? (s0 ? accr[3][0] : accr[2][0])
                            : (s0 ? accr[1][0] : accr[0][0]);
        const float r = sigmoid_f(fmaf(xt, wihr, br) + ar);

        // ---- n gate: tiles 8..11 (units 128..191) ----
        f32x4 accn[4];
#pragma unroll
        for (int q = 0; q < 4; ++q) {
            f32x4 c0 = __builtin_amdgcn_mfma_f32_16x16x32_f16(A0, Bf[8 + q][0], zf, 0, 0, 0);
            accn[q]  = __builtin_amdgcn_mfma_f32_16x16x32_f16(A1, Bf[8 + q][1], c0, 0, 0, 0);
        }
        const float an = s1 ? (s0 ? accn[3][0] : accn[2][0])
                            : (s0 ? accn[1][0] : accn[0][0]);
        const float n = tanh_f(fmaf(xt, wihn, bin) + r * (an + bhn));

        // ---- z gate: tiles 4..7 (units 64..127) ----
        f32x4 accz[4];
#pragma unroll
        for (int q = 0; q < 4; ++q) {
            f32x4 c0 = __builtin_amdgcn_mfma_f32_16x16x32_f16(A0, Bf[4 + q][0], zf, 0, 0, 0);
            accz[q]  = __builtin_amdgcn_mfma_f32_16x16x32_f16(A1, Bf[4 + q][1], c0, 0, 0, 0);
        }
        const float az = s1 ? (s0 ? accz[3][0] : accz[2][0])
                            : (s0 ? accz[1][0] : accz[0][0]);
        const float z = sigmoid_f(fmaf(xt, wihz, bz) + az);

        h = fmaf(z, h - n, n);  // (1-z)*n + z*h

        __builtin_amdgcn_wave_barrier();
        h_lds[l] = (f16)h;
        if (j == 63) {
            x_lds[l] = xnxt;
            const int idx = t + 65 + l;  // chunk after next
            xnxt = (idx < T_LEN) ? x[xbase + idx] : 0.0f;
        }
        __builtin_amdgcn_wave_barrier();
    }

    // ---- epilogue: out[b] = h . W_fc + b_fc (fp32) ----
    float v = h * W_fc[l];
#pragma unroll
    for (int off = 32; off > 0; off >>= 1) v += __shfl_down(v, off);
    if (l == 0) out[b] = v + b_fc[0];
}

extern "C" void kernel_launch(void* const* d_in, const int* in_sizes, int n_in,
                              void* d_out, int out_size, void* d_ws, size_t ws_size,
                              hipStream_t stream) {
    const float* x    = (const float*)d_in[0];
    const float* W_ih = (const float*)d_in[1];
    const float* W_hh = (const float*)d_in[2];
    const float* b_ih = (const float*)d_in[3];
    const float* b_hh = (const float*)d_in[4];
    const float* W_fc = (const float*)d_in[5];
    const float* b_fc = (const float*)d_in[6];
    float* out = (float*)d_out;

    const int B = 256;  // in_sizes[0] = B*T = 768000 -> B=256, T=3000
    gru_mfma<<<B, 64, 0, stream>>>(x, W_ih, W_hh, b_ih, b_hh, W_fc, b_fc, out);
}